// Round 1
// baseline (387.082 us; speedup 1.0000x reference)
//
#include <hip/hip_runtime.h>
#include <math.h>

// Problem constants (from reference)
#define B_ 16
#define P_ 131072
#define G_ 32
constexpr float OVER_THR = 0.35f;
constexpr float VAR0 = 0.1f;
constexpr float VAR1 = 0.2f;
constexpr int NEG_POS = 7;
constexpr int UNR = 4;                    // priors per thread in k_match
constexpr int LOSS_BLOCKS = (P_ / 256) * B_;   // 8192 partials from k_loss

// ---------------- helpers ----------------
__device__ inline float s1(float d) {            // smooth L1
    d = fabsf(d);
    return d < 1.f ? 0.5f * d * d : d - 0.5f;
}

__device__ inline unsigned long long shfl_xor_u64(unsigned long long x, int m) {
    unsigned lo = (unsigned)x, hi = (unsigned)(x >> 32);
    lo = __shfl_xor(lo, m);
    hi = __shfl_xor(hi, m);
    return ((unsigned long long)hi << 32) | lo;
}

// ---------------- kernels ----------------
__global__ void k_init(double* tot, int* npos, unsigned long long* pack) {
    int t = threadIdx.x;
    if (t < 4) tot[t] = 0.0;
    if (t < B_) npos[t] = 0;
    for (int i = t; i < B_ * G_; i += blockDim.x) pack[i] = 0ull;
}

// For each (b, prior): best truth (max IoU, first index on ties) -> bt_ov/bt_idx.
// For each (b, truth): best prior via packed (iou_bits<<32)|~p atomicMax.
__global__ __launch_bounds__(256) void k_match(
        const float4* __restrict__ priors4, const float* __restrict__ targets,
        float* __restrict__ bt_ov, int* __restrict__ bt_idx,
        unsigned long long* __restrict__ pack) {
    const int b = blockIdx.y;
    const int base = blockIdx.x * (256 * UNR);
    const int tid = threadIdx.x;
    __shared__ float tb[G_][5];                 // x1 y1 x2 y2 area
    __shared__ unsigned long long red[G_][4];
    if (tid < G_ * 4) {
        int g = tid >> 2, j = tid & 3;
        tb[g][j] = targets[((size_t)b * G_ + g) * 15 + j];
    }
    __syncthreads();
    if (tid < G_) tb[tid][4] = (tb[tid][2] - tb[tid][0]) * (tb[tid][3] - tb[tid][1]);
    __syncthreads();

    float px1[UNR], py1[UNR], px2[UNR], py2[UNR], pap[UNR], best[UNR];
    int bidx[UNR];
#pragma unroll
    for (int j = 0; j < UNR; ++j) {
        float4 pr = priors4[base + j * 256 + tid];
        px1[j] = pr.x - pr.z * 0.5f;  py1[j] = pr.y - pr.w * 0.5f;
        px2[j] = pr.x + pr.z * 0.5f;  py2[j] = pr.y + pr.w * 0.5f;
        pap[j] = pr.z * pr.w;
        best[j] = -1.0f; bidx[j] = 0;
    }
    const int lane = tid & 63, wave = tid >> 6;
#pragma unroll
    for (int g = 0; g < G_; ++g) {
        float t0 = tb[g][0], t1 = tb[g][1], t2 = tb[g][2], t3 = tb[g][3], ta = tb[g][4];
        unsigned long long pk = 0ull;
#pragma unroll
        for (int j = 0; j < UNR; ++j) {
            float iw = fminf(t2, px2[j]) - fmaxf(t0, px1[j]);
            float ih = fminf(t3, py2[j]) - fmaxf(t1, py1[j]);
            float inter = fmaxf(iw, 0.f) * fmaxf(ih, 0.f);
            float iou = inter / (ta + pap[j] - inter);
            if (iou > best[j]) { best[j] = iou; bidx[j] = g; }   // first-wins ties
            unsigned p = (unsigned)(base + j * 256 + tid);
            unsigned long long cand =
                ((unsigned long long)__float_as_uint(iou) << 32) | (unsigned)(~p);
            if (cand > pk) pk = cand;                            // lowest p wins ties
        }
#pragma unroll
        for (int off = 32; off > 0; off >>= 1) {
            unsigned long long o = shfl_xor_u64(pk, off);
            if (o > pk) pk = o;
        }
        if (lane == 0) red[g][wave] = pk;
    }
    __syncthreads();
    if (tid < G_) {
        unsigned long long m = red[tid][0];
#pragma unroll
        for (int w = 1; w < 4; ++w) if (red[tid][w] > m) m = red[tid][w];
        atomicMax(&pack[b * G_ + tid], m);
    }
#pragma unroll
    for (int j = 0; j < UNR; ++j) {
        int p = base + j * 256 + tid;
        size_t o = (size_t)b * P_ + p;
        bt_ov[o] = best[j];
        bt_idx[o] = bidx[j];
    }
}

// Sequential per image: scatter with last-g-wins (numpy semantics).
__global__ void k_override(const unsigned long long* __restrict__ pack,
                           float* __restrict__ bt_ov, int* __restrict__ bt_idx) {
    int b = threadIdx.x;
    if (b >= B_) return;
    for (int g = 0; g < G_; ++g) {
        unsigned long long pk = pack[b * G_ + g];
        unsigned p = ~(unsigned)(pk & 0xFFFFFFFFull);
        bt_ov[(size_t)b * P_ + p] = 2.0f;
        bt_idx[(size_t)b * P_ + p] = g;
    }
}

// Per prior: CE; positives: smooth-L1 on encoded loc/landm. Partials per block.
__global__ __launch_bounds__(256) void k_loss(
        const float2* __restrict__ conf2, const float4* __restrict__ loc4,
        const float* __restrict__ landm, const float4* __restrict__ priors4,
        const float* __restrict__ targets,
        const float* __restrict__ bt_ov, const int* __restrict__ bt_idx,
        float* __restrict__ ce_neg,
        double* __restrict__ pb, double* __restrict__ pl,
        double* __restrict__ pc, int* __restrict__ pn) {
    const int b = blockIdx.y;
    const int p = blockIdx.x * 256 + threadIdx.x;
    const int tid = threadIdx.x;
    __shared__ float tg[G_ * 15];
    for (int i = tid; i < G_ * 15; i += 256) tg[i] = targets[(size_t)b * G_ * 15 + i];
    __syncthreads();

    const size_t gp = (size_t)b * P_ + p;
    float ov = bt_ov[gp];
    int ti = bt_idx[gp];
    const float* t = &tg[ti * 15];
    float label = t[14];
    int conf_t = (ov < OVER_THR) ? 0 : (int)label;
    bool pos = conf_t > 0;
    int cls = conf_t > 0 ? conf_t : 0;

    float2 c2 = conf2[gp];
    float mx = fmaxf(c2.x, c2.y);
    float lse = mx + logf(expf(c2.x - mx) + expf(c2.y - mx));
    float ce = lse - (cls ? c2.y : c2.x);
    ce_neg[gp] = (!pos && conf_t >= 0) ? ce : 0.f;

    float lb = 0.f, ll = 0.f;
    if (pos) {
        float4 pr = priors4[p];
        float vx = VAR0 * pr.z, vy = VAR0 * pr.w;
        float g0 = ((t[0] + t[2]) * 0.5f - pr.x) / vx;
        float g1 = ((t[1] + t[3]) * 0.5f - pr.y) / vy;
        float g2 = logf((t[2] - t[0]) / pr.z) / VAR1;
        float g3 = logf((t[3] - t[1]) / pr.w) / VAR1;
        float4 ld = loc4[gp];
        lb = s1(ld.x - g0) + s1(ld.y - g1) + s1(ld.z - g2) + s1(ld.w - g3);
        const float* lmp = landm + gp * 10;
#pragma unroll
        for (int i = 0; i < 5; ++i) {
            float2 lm = *(const float2*)(lmp + 2 * i);
            ll += s1(lm.x - (t[4 + 2 * i] - pr.x) / vx)
                + s1(lm.y - (t[5 + 2 * i] - pr.y) / vy);
        }
    }
    double vb = lb, vl = ll, vc = pos ? (double)ce : 0.0;
    int vp = pos ? 1 : 0;
#pragma unroll
    for (int off = 32; off > 0; off >>= 1) {
        vb += __shfl_xor(vb, off);
        vl += __shfl_xor(vl, off);
        vc += __shfl_xor(vc, off);
        vp += __shfl_xor(vp, off);
    }
    __shared__ double rb[4], rl[4], rc[4];
    __shared__ int rp[4];
    int lane = tid & 63, wave = tid >> 6;
    if (lane == 0) { rb[wave] = vb; rl[wave] = vl; rc[wave] = vc; rp[wave] = vp; }
    __syncthreads();
    if (tid == 0) {
        double sb = 0, sl = 0, sc = 0; int sp = 0;
        for (int w = 0; w < 4; ++w) { sb += rb[w]; sl += rl[w]; sc += rc[w]; sp += rp[w]; }
        int bi = blockIdx.y * gridDim.x + blockIdx.x;
        pb[bi] = sb; pl[bi] = sl; pc[bi] = sc; pn[bi] = sp;
    }
}

// Single block: reduce 8192 partials -> totals + per-image num_pos.
__global__ __launch_bounds__(1024) void k_reduce(
        const double* __restrict__ pb, const double* __restrict__ pl,
        const double* __restrict__ pc, const int* __restrict__ pn,
        double* __restrict__ tot, int* __restrict__ npos) {
    __shared__ int snp[B_];
    int tid = threadIdx.x;
    if (tid < B_) snp[tid] = 0;
    __syncthreads();
    double sb = 0, sl = 0, sc = 0;
    for (int i = tid; i < LOSS_BLOCKS; i += 1024) {
        sb += pb[i]; sl += pl[i]; sc += pc[i];
        atomicAdd(&snp[i >> 9], pn[i]);        // 512 blocks per image
    }
#pragma unroll
    for (int off = 32; off > 0; off >>= 1) {
        sb += __shfl_xor(sb, off);
        sl += __shfl_xor(sl, off);
        sc += __shfl_xor(sc, off);
    }
    __shared__ double rb[16], rl[16], rc[16];
    int lane = tid & 63, wave = tid >> 6;
    if (lane == 0) { rb[wave] = sb; rl[wave] = sl; rc[wave] = sc; }
    __syncthreads();
    if (tid == 0) {
        double b2 = 0, l2 = 0, c2 = 0;
        for (int w = 0; w < 16; ++w) { b2 += rb[w]; l2 += rl[w]; c2 += rc[w]; }
        tot[0] = b2; tot[1] = l2; tot[2] = c2;   // box, landm, ce(pos part)
    }
    if (tid < B_) npos[tid] = snp[tid];
}

// Per image: radix-select k-th largest loss_c, add top-k sum to tot[2].
__global__ __launch_bounds__(1024) void k_mine(
        const float* __restrict__ ce_neg, const int* __restrict__ npos,
        double* __restrict__ tot) {
    const int b = blockIdx.x;
    const float* v = ce_neg + (size_t)b * P_;
    __shared__ unsigned hist[256];
    __shared__ unsigned s_sel, s_rem;
    __shared__ double rs[16];
    __shared__ unsigned rc2[16];
    const int tid = threadIdx.x;
    int np = npos[b];
    long long k = (long long)NEG_POS * np;
    if (k > P_ - 1) k = P_ - 1;
    if (k <= 0) return;                       // uniform per block
    unsigned rem = (unsigned)k;
    unsigned prefix = 0;
    for (int pass = 0; pass < 4; ++pass) {
        int shift = 24 - 8 * pass;
        for (int i = tid; i < 256; i += 1024) hist[i] = 0;
        __syncthreads();
        for (int i = tid; i < P_; i += 1024) {
            unsigned u = __float_as_uint(v[i]);
            bool okp = (pass == 0) || ((u >> (shift + 8)) == prefix);
            if (okp) atomicAdd(&hist[(u >> shift) & 255u], 1u);
        }
        __syncthreads();
        if (tid == 0) {
            unsigned c = 0; int sel = 0; unsigned nr = rem;
            for (int bin = 255; bin >= 0; --bin) {
                c += hist[bin];
                if (c >= rem) { sel = bin; nr = rem - (c - hist[bin]); break; }
            }
            s_sel = (unsigned)sel; s_rem = nr;
        }
        __syncthreads();
        prefix = (prefix << 8) | s_sel;
        rem = s_rem;
        __syncthreads();
    }
    float T = __uint_as_float(prefix);
    double sgt = 0; unsigned cgt = 0;
    for (int i = tid; i < P_; i += 1024) {
        float x = v[i];
        unsigned u = __float_as_uint(x);
        if (u > prefix) { sgt += x; cgt++; }
    }
#pragma unroll
    for (int off = 32; off > 0; off >>= 1) {
        sgt += __shfl_xor(sgt, off);
        cgt += __shfl_xor(cgt, off);
    }
    int lane = tid & 63, wave = tid >> 6;
    if (lane == 0) { rs[wave] = sgt; rc2[wave] = cgt; }
    __syncthreads();
    if (tid == 0) {
        double s = 0; unsigned c = 0;
        for (int w = 0; w < 16; ++w) { s += rs[w]; c += rc2[w]; }
        s += (double)(k - (long long)c) * (double)T;   // ties at threshold
        atomicAdd(&tot[2], s);
    }
}

__global__ void k_final(const double* __restrict__ tot,
                        const int* __restrict__ npos, float* __restrict__ out) {
    if (threadIdx.x == 0) {
        long long tp = 0;
        for (int b = 0; b < B_; ++b) tp += npos[b];
        double n = tp > 0 ? (double)tp : 1.0;
        out[0] = (float)(tot[0] / n);   // loss_box
        out[1] = (float)(tot[2] / n);   // loss_c
        out[2] = (float)(tot[1] / n);   // loss_landm
    }
}

// ---------------- launch ----------------
extern "C" void kernel_launch(void* const* d_in, const int* in_sizes, int n_in,
                              void* d_out, int out_size, void* d_ws, size_t ws_size,
                              hipStream_t stream) {
    const float* conf    = (const float*)d_in[0];
    const float* loc     = (const float*)d_in[1];
    const float* landm   = (const float*)d_in[2];
    const float* priors  = (const float*)d_in[3];
    const float* targets = (const float*)d_in[4];

    char* ws = (char*)d_ws;
    double* tot = (double*)ws;                                   // 4 doubles
    int* npos = (int*)(ws + 64);                                 // 16 ints
    unsigned long long* pack = (unsigned long long*)(ws + 128);  // 512 u64
    size_t BP = (size_t)B_ * P_;
    float* bt_ov = (float*)(ws + 8192);
    int*   bt_idx = (int*)(ws + 8192 + BP * 4);
    float* ce_neg = (float*)(ws + 8192 + BP * 8);
    char* part = ws + 8192 + BP * 12;
    double* pb = (double*)part;
    double* pl = (double*)(part + LOSS_BLOCKS * 8);
    double* pc = (double*)(part + LOSS_BLOCKS * 16);
    int*    pn = (int*)(part + LOSS_BLOCKS * 24);

    k_init<<<1, 512, 0, stream>>>(tot, npos, pack);
    k_match<<<dim3(P_ / (256 * UNR), B_), 256, 0, stream>>>(
        (const float4*)priors, targets, bt_ov, bt_idx, pack);
    k_override<<<1, 64, 0, stream>>>(pack, bt_ov, bt_idx);
    k_loss<<<dim3(P_ / 256, B_), 256, 0, stream>>>(
        (const float2*)conf, (const float4*)loc, landm, (const float4*)priors,
        targets, bt_ov, bt_idx, ce_neg, pb, pl, pc, pn);
    k_reduce<<<1, 1024, 0, stream>>>(pb, pl, pc, pn, tot, npos);
    k_mine<<<B_, 1024, 0, stream>>>(ce_neg, npos, tot);
    k_final<<<1, 64, 0, stream>>>(tot, npos, (float*)d_out);
}